// Round 1
// baseline (238.435 us; speedup 1.0000x reference)
//
#include <hip/hip_runtime.h>
#include <math.h>

#define NTOK   8192
#define HID    2048
#define NEXP   64
#define TOPK   8
#define NFLAT  (NTOK * TOPK)      // 65536
#define NB     256                // blocks for route/hist/pos (256 flat entries each)
#define OUT_GS_OFF  ((size_t)NFLAT * HID)        // 134217728
#define OUT_LB_OFF  (OUT_GS_OFF + NEXP)          // 134217792

// ---------------------------------------------------------------------------
// K1: per-token softmax + top-8 + per-block expert histogram + prob partials.
// 256 blocks x 256 threads (4 waves). Each wave handles one token per iter,
// 8 iters -> 32 tokens/block. lane == expert id.
// ---------------------------------------------------------------------------
__global__ __launch_bounds__(256) void k_route(const float* __restrict__ logits,
                                               int*   __restrict__ flat_idx,
                                               float* __restrict__ flat_w,
                                               int*   __restrict__ counts,     // [NEXP][NB]
                                               float* __restrict__ probpart) { // [NB][NEXP]
    __shared__ float sm[4][64];
    __shared__ int   cnt[64];
    const int tid  = threadIdx.x;
    const int lane = tid & 63;
    const int wave = tid >> 6;
    if (tid < 64) cnt[tid] = 0;
    float acc = 0.f;
    __syncthreads();

    for (int it = 0; it < 8; ++it) {
        const int token = blockIdx.x * 32 + it * 4 + wave;
        const float lg = logits[(size_t)token * NEXP + lane];
        // softmax across the 64-lane wave
        float m = lg;
        #pragma unroll
        for (int off = 32; off; off >>= 1) m = fmaxf(m, __shfl_xor(m, off));
        const float ex = expf(lg - m);
        float s = ex;
        #pragma unroll
        for (int off = 32; off; off >>= 1) s += __shfl_xor(s, off);
        const float p = ex / s;
        acc += p;

        // top-8: iterative max with lower-index tie-break (lax.top_k semantics)
        float v = p;
        float myv = 0.f; int myi = 0;
        float sum8 = 0.f;
        #pragma unroll
        for (int k = 0; k < TOPK; ++k) {
            float mv = v; int mi = lane;
            #pragma unroll
            for (int off = 32; off; off >>= 1) {
                const float ov = __shfl_xor(mv, off);
                const int   oi = __shfl_xor(mi, off);
                if (ov > mv || (ov == mv && oi < mi)) { mv = ov; mi = oi; }
            }
            if (lane == k)  { myv = mv; myi = mi; }
            if (lane == mi) v = -1.f;   // probs > 0, so -1 acts as -inf
            sum8 += mv;
        }
        if (lane < TOPK) {
            flat_idx[(size_t)token * TOPK + lane] = myi;
            flat_w  [(size_t)token * TOPK + lane] = myv / sum8;
            atomicAdd(&cnt[myi], 1);    // integer LDS atomic: order-independent
        }
    }

    sm[wave][lane] = acc;
    __syncthreads();
    if (tid < 64) {
        probpart[(size_t)blockIdx.x * 64 + tid] =
            sm[0][tid] + sm[1][tid] + sm[2][tid] + sm[3][tid];
        counts[(size_t)tid * NB + blockIdx.x] = cnt[tid];
    }
}

// ---------------------------------------------------------------------------
// K2: single block, 64 threads (1 wave). Per-expert scan across the 256
// block-histograms, exclusive scan over experts, group_sizes + lb_loss out.
// Fully deterministic serial reductions.
// ---------------------------------------------------------------------------
__global__ __launch_bounds__(64) void k_scan(int*   __restrict__ counts,    // [NEXP][NB] in
                                             int*   __restrict__ blockoff,  // [NEXP][NB] out
                                             const float* __restrict__ probpart,
                                             float* __restrict__ out_gs,
                                             float* __restrict__ out_lb) {
    __shared__ int   totals[64];
    __shared__ float psums[64];
    __shared__ int   basesm[64];
    const int e = threadIdx.x;

    int tot = 0;
    for (int b = 0; b < NB; ++b) {
        blockoff[(size_t)e * NB + b] = tot;
        tot += counts[(size_t)e * NB + b];
    }
    totals[e] = tot;
    float ps = 0.f;
    for (int b = 0; b < NB; ++b) ps += probpart[(size_t)b * 64 + e];
    psums[e] = ps;
    __syncthreads();

    if (e == 0) {
        int bacc = 0; float lb = 0.f;
        for (int i = 0; i < 64; ++i) {
            basesm[i] = bacc;
            bacc += totals[i];
            // f = counts/8192, p = probsum/8192
            lb += ((float)totals[i] * (1.f / 8192.f)) * (psums[i] * (1.f / 8192.f));
        }
        *out_lb = 0.01f * lb;
    }
    __syncthreads();

    out_gs[e] = (float)totals[e];
    const int be = basesm[e];
    for (int b = 0; b < NB; ++b) blockoff[(size_t)e * NB + b] += be;
}

// ---------------------------------------------------------------------------
// K3: destination row per flat entry = blockoff[e][blk] + stable intra-block
// rank (O(256) LDS loop — 65536 entries total, trivial).
// ---------------------------------------------------------------------------
__global__ __launch_bounds__(256) void k_pos(const int* __restrict__ flat_idx,
                                             const int* __restrict__ blockoff,
                                             int*       __restrict__ pos) {
    __shared__ int ids[256];
    const int t = threadIdx.x;
    const int g = blockIdx.x * 256 + t;
    const int e = flat_idx[g];
    ids[t] = e;
    __syncthreads();
    int r = 0;
    for (int j = 0; j < t; ++j) r += (ids[j] == e);
    pos[g] = blockoff[(size_t)e * NB + blockIdx.x] + r;
}

// ---------------------------------------------------------------------------
// K4: the heavy copy. One block per output row: read token row (L3-resident),
// scale, write to permuted destination. float4 x2 per thread, coalesced.
// ---------------------------------------------------------------------------
__global__ __launch_bounds__(256) void k_copy(const float* __restrict__ x,
                                              const int*   __restrict__ pos,
                                              const float* __restrict__ flat_w,
                                              float*       __restrict__ out) {
    const int g = blockIdx.x;
    const int token = g >> 3;
    const float w = flat_w[g];
    const int r = pos[g];
    const float4* __restrict__ src = (const float4*)(x + (size_t)token * HID);
    float4*       __restrict__ dst = (float4*)(out + (size_t)r * HID);
    const int t = threadIdx.x;
    float4 a = src[t];
    float4 b = src[t + 256];
    a.x *= w; a.y *= w; a.z *= w; a.w *= w;
    b.x *= w; b.y *= w; b.z *= w; b.w *= w;
    dst[t] = a;
    dst[t + 256] = b;
}

extern "C" void kernel_launch(void* const* d_in, const int* in_sizes, int n_in,
                              void* d_out, int out_size, void* d_ws, size_t ws_size,
                              hipStream_t stream) {
    const float* x      = (const float*)d_in[0];   // inputs_flat [8192,2048]
    const float* logits = (const float*)d_in[1];   // router_logits [8192,64]
    float* out = (float*)d_out;

    char* ws = (char*)d_ws;
    int*   flat_idx = (int*)  (ws + 0);            // 65536 * 4 = 262144
    float* flat_w   = (float*)(ws + 262144);       // 262144
    int*   pos      = (int*)  (ws + 524288);       // 262144
    int*   counts   = (int*)  (ws + 786432);       // 64*256*4 = 65536
    int*   blockoff = (int*)  (ws + 851968);       // 65536
    float* probpart = (float*)(ws + 917504);       // 256*64*4 = 65536

    k_route<<<NB, 256, 0, stream>>>(logits, flat_idx, flat_w, counts, probpart);
    k_scan <<<1, 64, 0, stream>>>(counts, blockoff, probpart,
                                  out + OUT_GS_OFF, out + OUT_LB_OFF);
    k_pos  <<<NB, 256, 0, stream>>>(flat_idx, blockoff, pos);
    k_copy <<<NFLAT, 256, 0, stream>>>(x, pos, flat_w, out);
}

// Round 3
// 163.331 us; speedup vs baseline: 1.4598x; 1.4598x over previous
//
#include <hip/hip_runtime.h>
#include <math.h>

#define NTOK   8192
#define HID    2048
#define NEXP   64
#define TOPK   8
#define NFLAT  (NTOK * TOPK)      // 65536
#define NB     256                // route blocks (32 tokens each)
#define OUT_GS_OFF  ((size_t)NFLAT * HID)        // 134217728
#define OUT_LB_OFF  (OUT_GS_OFF + NEXP)          // 134217792

typedef float f32x4 __attribute__((ext_vector_type(4)));

// ---------------------------------------------------------------------------
// K1: per-token softmax + top-8 + per-block expert bitmasks (stable rank) +
// prob partials. 256 blocks x 256 threads (4 waves), 32 tokens/block.
// lane == expert id. Entry metadata packed as e | (rank<<8).
// ---------------------------------------------------------------------------
__global__ __launch_bounds__(256) void k_route(const float* __restrict__ logits,
                                               int*   __restrict__ e_rank,   // [NFLAT]
                                               float* __restrict__ flat_w,   // [NFLAT]
                                               int*   __restrict__ counts,   // [NEXP][NB]
                                               float* __restrict__ probpart) // [NEXP][NB]
{
    __shared__ float sm[4][64];
    __shared__ unsigned mask[64];     // bit ti set if block-token ti chose expert
    const int tid  = threadIdx.x;
    const int lane = tid & 63;
    const int wave = tid >> 6;
    if (tid < 64) mask[tid] = 0u;
    float acc = 0.f;
    __syncthreads();

    int   sel_i[8];
    float sel_v[8];
    float sum8s[8];

    #pragma unroll
    for (int it = 0; it < 8; ++it) {
        const int ti    = it * 4 + wave;            // token index within block
        const int token = blockIdx.x * 32 + ti;
        const float lg = logits[(size_t)token * NEXP + lane];
        // softmax across the 64-lane wave
        float m = lg;
        #pragma unroll
        for (int off = 32; off; off >>= 1) m = fmaxf(m, __shfl_xor(m, off));
        const float ex = expf(lg - m);
        float s = ex;
        #pragma unroll
        for (int off = 32; off; off >>= 1) s += __shfl_xor(s, off);
        const float p = ex / s;
        acc += p;

        // top-8: iterative max with lower-index tie-break (lax.top_k semantics)
        float v = p;
        float mysel_v = 0.f; int mysel_i = 0; float sum8 = 0.f;
        #pragma unroll
        for (int k = 0; k < TOPK; ++k) {
            float mv = v; int mi = lane;
            #pragma unroll
            for (int off = 32; off; off >>= 1) {
                const float ov = __shfl_xor(mv, off);
                const int   oi = __shfl_xor(mi, off);
                if (ov > mv || (ov == mv && oi < mi)) { mv = ov; mi = oi; }
            }
            if (lane == k)  { mysel_v = mv; mysel_i = mi; }
            if (lane == mi) v = -1.f;   // probs > 0, so -1 acts as -inf
            sum8 += mv;
        }
        sel_i[it] = mysel_i; sel_v[it] = mysel_v; sum8s[it] = sum8;
        if (lane < TOPK) atomicOr(&mask[mysel_i], 1u << ti);
    }

    sm[wave][lane] = acc;
    __syncthreads();

    if (tid < 64) {
        counts  [(size_t)tid * NB + blockIdx.x] = (int)__popc(mask[tid]);
        probpart[(size_t)tid * NB + blockIdx.x] =
            sm[0][tid] + sm[1][tid] + sm[2][tid] + sm[3][tid];
    }

    // stable intra-block rank: # earlier block-tokens that chose the same expert
    #pragma unroll
    for (int it = 0; it < 8; ++it) {
        const int ti    = it * 4 + wave;
        const int token = blockIdx.x * 32 + ti;
        if (lane < TOPK) {
            const int e    = sel_i[it];
            const int rank = (int)__popc(mask[e] & ((1u << ti) - 1u));
            e_rank[(size_t)token * TOPK + lane] = e | (rank << 8);
            flat_w[(size_t)token * TOPK + lane] = sel_v[it] / sum8s[it];
        }
    }
}

// ---------------------------------------------------------------------------
// K2: single block, 64 threads. int4/float4-vectorized per-expert scan across
// 256 block-histograms; expert base folded into blockoff. group_sizes + lb.
// ---------------------------------------------------------------------------
__global__ __launch_bounds__(64) void k_scan(const int*   __restrict__ counts,   // [NEXP][NB]
                                             const float* __restrict__ probpart, // [NEXP][NB]
                                             int*   __restrict__ blockoff,       // [NEXP][NB]
                                             float* __restrict__ out_gs,
                                             float* __restrict__ out_lb) {
    __shared__ int   totals[64];
    __shared__ float psums[64];
    __shared__ int   basesm[64];
    const int e = threadIdx.x;

    int tot = 0; float ps = 0.f;
    for (int b = 0; b < NB; b += 4) {
        const int4   c = *(const int4*)  &counts  [(size_t)e * NB + b];
        const float4 q = *(const float4*)&probpart[(size_t)e * NB + b];
        tot += c.x + c.y + c.z + c.w;
        ps  += q.x + q.y + q.z + q.w;
    }
    totals[e] = tot; psums[e] = ps;
    __syncthreads();

    if (e == 0) {
        int bacc = 0; float lb = 0.f;
        for (int i = 0; i < 64; ++i) {
            basesm[i] = bacc;
            bacc += totals[i];
            lb += ((float)totals[i] * (1.f / 8192.f)) * (psums[i] * (1.f / 8192.f));
        }
        *out_lb = 0.01f * lb;
    }
    __syncthreads();

    out_gs[e] = (float)totals[e];
    int run = basesm[e];
    for (int b = 0; b < NB; b += 4) {
        const int4 c = *(const int4*)&counts[(size_t)e * NB + b];
        int4 o;
        o.x = run;
        o.y = o.x + c.x;
        o.z = o.y + c.y;
        o.w = o.z + c.z;
        run = o.w + c.w;
        *(int4*)&blockoff[(size_t)e * NB + b] = o;
    }
}

// ---------------------------------------------------------------------------
// K3: one block per TOKEN — read the 8 KB row ONCE from HBM, write 8 scaled
// copies to permuted destinations with nontemporal stores (output never
// re-read; keep it out of L2/L3 so x stays resident).
// ---------------------------------------------------------------------------
__global__ __launch_bounds__(256) void k_copy(const float* __restrict__ x,
                                              const int*   __restrict__ e_rank,
                                              const float* __restrict__ flat_w,
                                              const int*   __restrict__ blockoff,
                                              float*       __restrict__ out) {
    const int token = blockIdx.x;
    __shared__ int   s_pos[8];
    __shared__ float s_w[8];
    const int t = threadIdx.x;
    if (t < TOPK) {
        const int er   = e_rank[(size_t)token * TOPK + t];
        const int e    = er & 0xff;
        const int rank = er >> 8;
        s_pos[t] = blockoff[(size_t)e * NB + (token >> 5)] + rank;
        s_w[t]   = flat_w[(size_t)token * TOPK + t];
    }
    __syncthreads();

    const f32x4* __restrict__ src = (const f32x4*)(x + (size_t)token * HID);
    const f32x4 a = src[t];
    const f32x4 b = src[t + 256];

    #pragma unroll
    for (int k = 0; k < TOPK; ++k) {
        const float w = s_w[k];
        f32x4* dst = (f32x4*)(out + (size_t)s_pos[k] * HID);
        const f32x4 aw = a * w;
        const f32x4 bw = b * w;
        __builtin_nontemporal_store(aw, dst + t);
        __builtin_nontemporal_store(bw, dst + t + 256);
    }
}

extern "C" void kernel_launch(void* const* d_in, const int* in_sizes, int n_in,
                              void* d_out, int out_size, void* d_ws, size_t ws_size,
                              hipStream_t stream) {
    const float* x      = (const float*)d_in[0];   // inputs_flat [8192,2048]
    const float* logits = (const float*)d_in[1];   // router_logits [8192,64]
    float* out = (float*)d_out;

    char* ws = (char*)d_ws;
    int*   e_rank   = (int*)  (ws + 0);            // 65536*4 = 262144
    float* flat_w   = (float*)(ws + 262144);       // 262144
    int*   counts   = (int*)  (ws + 524288);       // 64*256*4 = 65536
    int*   blockoff = (int*)  (ws + 589824);       // 65536
    float* probpart = (float*)(ws + 655360);       // 65536

    k_route<<<NB, 256, 0, stream>>>(logits, e_rank, flat_w, counts, probpart);
    k_scan <<<1, 64, 0, stream>>>(counts, probpart, blockoff,
                                  out + OUT_GS_OFF, out + OUT_LB_OFF);
    k_copy <<<NTOK, 256, 0, stream>>>(x, e_rank, flat_w, blockoff, out);
}